// Round 1
// baseline (89.047 us; speedup 1.0000x reference)
//
#include <hip/hip_runtime.h>

#define BB 4
#define NN 512
#define KK 512
#define DD 64
// TAU = 4.0  ->  softmax scale 0.25; b2 dropped (constant shift, softmax-invariant)

// ---------------- Kernel A: hk[b*512+k][e] = sum_d K[b,k,d] * W1[2d+1][e] ----------------
__global__ __launch_bounds__(256) void mlpattn_hk(const float* __restrict__ Kp,
                                                  const float* __restrict__ W1,
                                                  float* __restrict__ hk) {
    const int lane = threadIdx.x & 63;
    const int wave = threadIdx.x >> 6;
    const int gw = blockIdx.x * 4 + wave;   // 0..1023
    const int r0 = gw * 2;                  // rows 0..2047 (b*512 + k)
    const float* x0 = Kp + (size_t)r0 * DD;
    const float* x1 = x0 + DD;
    float acc0 = 0.f, acc1 = 0.f;
#pragma unroll
    for (int d = 0; d < DD; ++d) {
        float w = W1[(2 * d + 1) * DD + lane];   // coalesced 256B, L1-hot
        acc0 = fmaf(x0[d], w, acc0);             // wave-uniform broadcast load
        acc1 = fmaf(x1[d], w, acc1);
    }
    hk[(size_t)r0 * DD + lane] = acc0;
    hk[(size_t)(r0 + 1) * DD + lane] = acc1;
}

// ---------------- Kernel B: block = (b, 4 query rows) ----------------
__global__ __launch_bounds__(256) void mlpattn_main(const float* __restrict__ Q,
                                                    const float* __restrict__ V,
                                                    const float* __restrict__ W1,
                                                    const float* __restrict__ b1,
                                                    const float* __restrict__ W2,
                                                    const float* __restrict__ hk,
                                                    float* __restrict__ out,
                                                    float* __restrict__ att_out) {
    __shared__ float s_hk[128 * 65];   // hk chunk, k-major, +1 pad (also aliased as PV partials)
    __shared__ float s_att[4 * 512];   // res -> att, 4 rows
    __shared__ float s_part[8 * 128];  // res partials: [slot(2)][row(4)][k(128)]
    __shared__ float s_hq[4 * 64];     // hq rows (+b1)
    __shared__ float s_w2[64];

    const int t = threadIdx.x;
    const int b = blockIdx.x >> 7;         // 0..3
    const int ng = blockIdx.x & 127;       // row group: rows ng*4 .. ng*4+3

    // ---- prologue: hq[row][e] = b1[e] + sum_d Q[b,row,d]*W1[2d][e], wave per row ----
    {
        const int lane = t & 63;
        const int row = t >> 6;
        const float* qrow = Q + ((size_t)b * NN + ng * 4 + row) * DD;
        float acc = 0.f;
#pragma unroll
        for (int d = 0; d < DD; ++d)
            acc = fmaf(qrow[d], W1[2 * d * DD + lane], acc);
        s_hq[row * 64 + lane] = acc + b1[lane];
        if (t < 64) s_w2[t] = W2[t];
    }
    __syncthreads();

    // per-thread W2 slice in registers
    const int k = t & 127;        // k within chunk
    const int slot = t >> 7;      // 0/1 -> d half
    const int d0 = slot * 32;
    float rw[32];
#pragma unroll
    for (int j = 0; j < 32; ++j) rw[j] = s_w2[d0 + j];

    const float4* HK4 = (const float4*)(hk + (size_t)b * KK * DD);

    // ---- res: 4 chunks of 128 k ----
    for (int kc = 0; kc < 4; ++kc) {
        // stage chunk: 2048 float4, coalesced global, conflict-free LDS writes
#pragma unroll
        for (int m = 0; m < 8; ++m) {
            int idx = m * 256 + t;
            int c = idx & 15;       // float4 column
            int kk = idx >> 4;      // 0..127
            float4 v = HK4[(size_t)(kc * 128 + kk) * 16 + c];
            float* dst = &s_hk[kk * 65 + c * 4];
            dst[0] = v.x; dst[1] = v.y; dst[2] = v.z; dst[3] = v.w;
        }
        __syncthreads();

        float acc0 = 0.f, acc1 = 0.f, acc2 = 0.f, acc3 = 0.f;
#pragma unroll
        for (int j = 0; j < 32; ++j) {
            int d = d0 + j;
            float hkv = s_hk[k * 65 + d];          // 2-way aliased: free
            float w = rw[j];
            float v0 = fmaxf(s_hq[d] + hkv, 0.f);          // broadcast reads
            float v1 = fmaxf(s_hq[64 + d] + hkv, 0.f);
            float v2 = fmaxf(s_hq[128 + d] + hkv, 0.f);
            float v3 = fmaxf(s_hq[192 + d] + hkv, 0.f);
            acc0 = fmaf(v0, w, acc0);
            acc1 = fmaf(v1, w, acc1);
            acc2 = fmaf(v2, w, acc2);
            acc3 = fmaf(v3, w, acc3);
        }
        s_part[(slot * 4 + 0) * 128 + k] = acc0;
        s_part[(slot * 4 + 1) * 128 + k] = acc1;
        s_part[(slot * 4 + 2) * 128 + k] = acc2;
        s_part[(slot * 4 + 3) * 128 + k] = acc3;
        __syncthreads();

        // combine the two d-halves -> res values into s_att
#pragma unroll
        for (int i = 0; i < 2; ++i) {
            int idx = i * 256 + t;
            int row = idx >> 7;
            int kk = idx & 127;
            s_att[row * 512 + kc * 128 + kk] =
                s_part[row * 128 + kk] + s_part[(4 + row) * 128 + kk];
        }
        // no barrier needed: next stage writes s_hk (disjoint from s_part/s_att);
        // next s_part writes are after the post-stage barrier.
    }
    __syncthreads();

    // ---- softmax: wave per row, fully in-wave butterfly reductions ----
    {
        const int lane = t & 63;
        const int row = t >> 6;
        float* sr = s_att + row * 512;
        float v[8];
        float mx = -1e30f;
#pragma unroll
        for (int i = 0; i < 8; ++i) { v[i] = sr[lane + 64 * i]; mx = fmaxf(mx, v[i]); }
#pragma unroll
        for (int off = 32; off; off >>= 1) mx = fmaxf(mx, __shfl_xor(mx, off, 64));
        float s = 0.f;
#pragma unroll
        for (int i = 0; i < 8; ++i) { v[i] = __expf((v[i] - mx) * 0.25f); s += v[i]; }
#pragma unroll
        for (int off = 32; off; off >>= 1) s += __shfl_xor(s, off, 64);
        float inv = 1.0f / s;
        float* ga = att_out + ((size_t)b * NN + ng * 4 + row) * KK;
#pragma unroll
        for (int i = 0; i < 8; ++i) {
            float a = v[i] * inv;
            sr[lane + 64 * i] = a;
            ga[lane + 64 * i] = a;      // coalesced att output
        }
    }
    __syncthreads();

    // ---- PV: out[row][d] = sum_k att[row][k] * V[b,k,d]; V read once for all 4 rows ----
    {
        const int dq = t & 15;      // float4 column over d
        const int kg = t >> 4;      // 0..15, 32 k each
        const float4* V4 = (const float4*)(V + (size_t)b * KK * DD);
        float4 a0 = {0, 0, 0, 0}, a1 = a0, a2 = a0, a3 = a0;
#pragma unroll
        for (int kk = 0; kk < 32; ++kk) {
            int k2 = kg * 32 + kk;
            float4 vv = V4[(size_t)k2 * 16 + dq];   // coalesced
            float p0 = s_att[k2];
            float p1 = s_att[512 + k2];
            float p2 = s_att[1024 + k2];
            float p3 = s_att[1536 + k2];
            a0.x = fmaf(p0, vv.x, a0.x); a0.y = fmaf(p0, vv.y, a0.y);
            a0.z = fmaf(p0, vv.z, a0.z); a0.w = fmaf(p0, vv.w, a0.w);
            a1.x = fmaf(p1, vv.x, a1.x); a1.y = fmaf(p1, vv.y, a1.y);
            a1.z = fmaf(p1, vv.z, a1.z); a1.w = fmaf(p1, vv.w, a1.w);
            a2.x = fmaf(p2, vv.x, a2.x); a2.y = fmaf(p2, vv.y, a2.y);
            a2.z = fmaf(p2, vv.z, a2.z); a2.w = fmaf(p2, vv.w, a2.w);
            a3.x = fmaf(p3, vv.x, a3.x); a3.y = fmaf(p3, vv.y, a3.y);
            a3.z = fmaf(p3, vv.z, a3.z); a3.w = fmaf(p3, vv.w, a3.w);
        }
        float4* pv4 = (float4*)s_hk;   // s_hk dead after res phase
        pv4[(kg * 4 + 0) * 16 + dq] = a0;
        pv4[(kg * 4 + 1) * 16 + dq] = a1;
        pv4[(kg * 4 + 2) * 16 + dq] = a2;
        pv4[(kg * 4 + 3) * 16 + dq] = a3;
    }
    __syncthreads();
    {
        const int row = t >> 6;
        const int d = t & 63;
        float s = 0.f;
#pragma unroll
        for (int kg = 0; kg < 16; ++kg) s += s_hk[kg * 256 + row * 64 + d];
        out[((size_t)b * NN + ng * 4 + row) * DD + d] = s;
    }
}

extern "C" void kernel_launch(void* const* d_in, const int* in_sizes, int n_in,
                              void* d_out, int out_size, void* d_ws, size_t ws_size,
                              hipStream_t stream) {
    const float* Q  = (const float*)d_in[0];
    const float* K  = (const float*)d_in[1];
    const float* V  = (const float*)d_in[2];
    const float* W1 = (const float*)d_in[3];
    const float* b1 = (const float*)d_in[4];
    const float* W2 = (const float*)d_in[5];
    // b2 (d_in[6]) is softmax-invariant -> unused

    float* out = (float*)d_out;                       // B*N*D = 131072 floats
    float* att = (float*)d_out + BB * NN * DD;        // B*N*K = 1048576 floats
    float* hk = (float*)d_ws;                         // 2048*64 floats = 512 KB

    mlpattn_hk<<<256, 256, 0, stream>>>(K, W1, hk);
    mlpattn_main<<<512, 256, 0, stream>>>(Q, V, W1, b1, W2, hk, out, att);
}

// Round 2
// 86.635 us; speedup vs baseline: 1.0278x; 1.0278x over previous
//
#include <hip/hip_runtime.h>

#define BB 4
#define NN 512
#define KK 512
#define DD 64
#define ROWS 8
// TAU = 4.0 -> softmax scale 0.25; b2 dropped (constant pre-softmax shift, softmax-invariant)

// ws layout (floats): hq_ws [2048][64] (b1 folded) | hkT_ws [4][16][512][4] (hk transposed)

// ---------------- Kernel A: hq = Q@Wq + b1 (row-major), hk = K@Wk (transposed layout) ----
__global__ __launch_bounds__(256) void mlpattn_proj(const float* __restrict__ Q,
                                                    const float* __restrict__ Kp,
                                                    const float* __restrict__ W1,
                                                    const float* __restrict__ b1,
                                                    float* __restrict__ hq_ws,
                                                    float* __restrict__ hkT_ws) {
    const int lane = threadIdx.x & 63;
    const int wave = threadIdx.x >> 6;
    const int half = blockIdx.x >> 8;          // 0 = hq blocks, 1 = hk blocks
    const int blk  = blockIdx.x & 255;
    const int r0 = (blk * 4 + wave) * 2;       // rows 0..2046 step 2 (b*512 + n/k)
    if (half == 0) {
        const float* x0 = Q + (size_t)r0 * DD;
        const float* x1 = x0 + DD;
        float acc0 = 0.f, acc1 = 0.f;
#pragma unroll
        for (int d = 0; d < DD; ++d) {
            float w = W1[(2 * d) * DD + lane];     // coalesced, L1-hot
            acc0 = fmaf(x0[d], w, acc0);           // x: wave-uniform -> s_load
            acc1 = fmaf(x1[d], w, acc1);
        }
        float bb = b1[lane];
        hq_ws[(size_t)r0 * DD + lane] = acc0 + bb;
        hq_ws[(size_t)(r0 + 1) * DD + lane] = acc1 + bb;
    } else {
        const float* x0 = Kp + (size_t)r0 * DD;
        const float* x1 = x0 + DD;
        float acc0 = 0.f, acc1 = 0.f;
#pragma unroll
        for (int d = 0; d < DD; ++d) {
            float w = W1[(2 * d + 1) * DD + lane];
            acc0 = fmaf(x0[d], w, acc0);
            acc1 = fmaf(x1[d], w, acc1);
        }
        const int b = r0 >> 9;
        const int k = r0 & 511;
        const int j4 = lane >> 2, c = lane & 3;    // hkT[b][j4][k][c] = hk[k][4*j4+c]
        float* dst = hkT_ws + ((size_t)(b * 16 + j4) * KK) * 4 + c;
        dst[(size_t)k * 4] = acc0;
        dst[(size_t)(k + 1) * 4] = acc1;
    }
}

// ---------------- Kernel B: block = (b, 8 query rows), 512 threads, thread t <-> k=t ----
__global__ __launch_bounds__(512, 2) void mlpattn_main(const float* __restrict__ V,
                                                       const float* __restrict__ W2,
                                                       const float* __restrict__ hq_ws,
                                                       const float* __restrict__ hkT_ws,
                                                       float* __restrict__ out,
                                                       float* __restrict__ att_out) {
    __shared__ float s_att[ROWS * KK];           // 16 KB
    __shared__ float4 s_pv[32 * ROWS * 16];      // 64 KB (kg, r, dq)

    const int t = threadIdx.x;                   // = k for the res phase
    const int b  = blockIdx.x >> 6;              // 0..3
    const int ng = blockIdx.x & 63;              // row group
    const int row0 = ng * ROWS;

    // ---- res: hk[k][:] in 64 VGPRs (coalesced), hq/W2 wave-uniform, inner loop pure VALU
    float hkreg[DD];
    {
        const float4* hkT4 = (const float4*)hkT_ws + (size_t)b * 16 * KK;
#pragma unroll
        for (int j4 = 0; j4 < 16; ++j4)
            *(float4*)&hkreg[j4 * 4] = hkT4[(size_t)j4 * KK + t];   // lanes consecutive
    }
    float w2r[DD];
#pragma unroll
    for (int j4 = 0; j4 < 16; ++j4)
        *(float4*)&w2r[j4 * 4] = ((const float4*)W2)[j4];           // uniform

    const float* hqb = hq_ws + ((size_t)b * NN + row0) * DD;
#pragma unroll
    for (int r = 0; r < ROWS; ++r) {
        float hq[DD];
#pragma unroll
        for (int j4 = 0; j4 < 16; ++j4)
            *(float4*)&hq[j4 * 4] = ((const float4*)(hqb + r * DD))[j4];  // uniform
        float a = 0.f;
#pragma unroll
        for (int j = 0; j < DD; ++j)
            a = fmaf(fmaxf(hq[j] + hkreg[j], 0.f), w2r[j], a);      // 3 VALU, 0 mem
        s_att[r * KK + t] = a;                                      // stride-1: conflict-free
    }
    __syncthreads();

    // ---- softmax: wave per row, in-wave butterfly ----
    {
        const int lane = t & 63;
        const int w = t >> 6;                    // row 0..7
        float* sr = s_att + w * KK;
        float v[8];
        float mx = -1e30f;
#pragma unroll
        for (int i = 0; i < 8; ++i) { v[i] = sr[lane + 64 * i]; mx = fmaxf(mx, v[i]); }
#pragma unroll
        for (int off = 32; off; off >>= 1) mx = fmaxf(mx, __shfl_xor(mx, off, 64));
        float s = 0.f;
#pragma unroll
        for (int i = 0; i < 8; ++i) { v[i] = __expf((v[i] - mx) * 0.25f); s += v[i]; }
#pragma unroll
        for (int off = 32; off; off >>= 1) s += __shfl_xor(s, off, 64);
        float inv = 1.0f / s;
        float* ga = att_out + ((size_t)b * NN + row0 + w) * KK;
#pragma unroll
        for (int i = 0; i < 8; ++i) {
            float a = v[i] * inv;
            sr[lane + 64 * i] = a;
            ga[lane + 64 * i] = a;               // coalesced att output
        }
    }
    __syncthreads();

    // ---- PV: thread (dq, kg) accumulates 16 k for all 8 rows; V read once per block ----
    {
        const int dq = t & 15;
        const int kg = t >> 4;                   // 0..31
        const float4* V4 = (const float4*)V + (size_t)b * KK * 16;
        float4 a[ROWS];
#pragma unroll
        for (int r = 0; r < ROWS; ++r) a[r] = make_float4(0.f, 0.f, 0.f, 0.f);
#pragma unroll
        for (int kk = 0; kk < 16; ++kk) {
            const int k = kg * 16 + kk;
            float4 vv = V4[(size_t)k * 16 + dq]; // 4x256B segments per wave instr
#pragma unroll
            for (int r = 0; r < ROWS; ++r) {
                float p = s_att[r * KK + k];     // 4-addr broadcast, ~free
                a[r].x = fmaf(p, vv.x, a[r].x);
                a[r].y = fmaf(p, vv.y, a[r].y);
                a[r].z = fmaf(p, vv.z, a[r].z);
                a[r].w = fmaf(p, vv.w, a[r].w);
            }
        }
#pragma unroll
        for (int r = 0; r < ROWS; ++r)
            s_pv[(kg * ROWS + r) * 16 + dq] = a[r];   // even bank spread
    }
    __syncthreads();

    // ---- reduce 32 kg partials -> out ----
    float4* s_red = (float4*)s_att;              // s_att dead after PV barrier
    {
        const int o = t & 127;                   // r*16+dq
        const int g = t >> 7;                    // 0..3
        float4 s = make_float4(0.f, 0.f, 0.f, 0.f);
#pragma unroll
        for (int i = 0; i < 8; ++i) {
            float4 p = s_pv[(g * 8 + i) * 128 + o];
            s.x += p.x; s.y += p.y; s.z += p.z; s.w += p.w;
        }
        s_red[g * 128 + o] = s;
    }
    __syncthreads();
    if (t < 128) {
        float4 s0 = s_red[t], s1 = s_red[128 + t], s2 = s_red[256 + t], s3 = s_red[384 + t];
        float4 s = make_float4(s0.x + s1.x + s2.x + s3.x,
                               s0.y + s1.y + s2.y + s3.y,
                               s0.z + s1.z + s2.z + s3.z,
                               s0.w + s1.w + s2.w + s3.w);
        const int r = t >> 4, dq = t & 15;
        ((float4*)out)[((size_t)b * NN + row0 + r) * 16 + dq] = s;
    }
}

extern "C" void kernel_launch(void* const* d_in, const int* in_sizes, int n_in,
                              void* d_out, int out_size, void* d_ws, size_t ws_size,
                              hipStream_t stream) {
    const float* Q  = (const float*)d_in[0];
    const float* K  = (const float*)d_in[1];
    const float* V  = (const float*)d_in[2];
    const float* W1 = (const float*)d_in[3];
    const float* b1 = (const float*)d_in[4];
    const float* W2 = (const float*)d_in[5];
    // b2 (d_in[6]) unused: softmax-invariant constant shift

    float* out = (float*)d_out;                        // B*N*D
    float* att = (float*)d_out + BB * NN * DD;         // B*N*K
    float* hq_ws  = (float*)d_ws;                      // 512 KB
    float* hkT_ws = (float*)d_ws + BB * NN * DD;       // 512 KB

    mlpattn_proj<<<512, 256, 0, stream>>>(Q, K, W1, b1, hq_ws, hkT_ws);
    mlpattn_main<<<256, 512, 0, stream>>>(V, W2, hq_ws, hkT_ws, out, att);
}